// Round 3
// baseline (4471.577 us; speedup 1.0000x reference)
//
#include <hip/hip_runtime.h>
#include <math.h>

#define N_USERS    50000
#define N_ENTITIES 100000
#define N_NODES    150000
#define EMBED_DIM  64
#define N_EDGES    2400000
#define BATCH      4096
#define NEG_SLOPE  0.01f
#define L2_EPS     1e-12f

// ---------------------------------------------------------------------------
// Scatter: h_neigh[target] += feat[neighbor] * value   (64-dim rows)
// 4 edges per wave: lane l -> edge (w*4 + (l>>4)), dims (l&15)*4 .. +3.
// Gather is one float4 (dwordx4) per lane; scatter is 4 consecutive f32
// atomicAdds per lane.
// ---------------------------------------------------------------------------
__global__ __launch_bounds__(256)
void scatter_kernel(const float* __restrict__ feat,
                    const int*   __restrict__ target,
                    const int*   __restrict__ neighbor,
                    const float* __restrict__ values,
                    float*       __restrict__ hneigh,
                    int nEdges) {
    const int lane   = threadIdx.x & 63;
    const int sub    = lane >> 4;        // which of the 4 edges this lane serves
    const int dlane  = lane & 15;        // float4 index within the 64-dim row
    const int gwave  = (blockIdx.x * blockDim.x + threadIdx.x) >> 6;
    const int nwaves = (gridDim.x * blockDim.x) >> 6;

    const float4* __restrict__ feat4 = (const float4*)feat;

    for (int base = gwave * 4; base < nEdges; base += nwaves * 4) {
        const int e = base + sub;
        if (e < nEdges) {
            const int   nbr = neighbor[e];
            const int   tgt = target[e];
            const float v   = values[e];

            float4 m = feat4[(size_t)nbr * 16 + dlane];
            m.x *= v; m.y *= v; m.z *= v; m.w *= v;

            float* dst = &hneigh[(size_t)tgt * 64 + dlane * 4];
            atomicAdd(dst + 0, m.x);
            atomicAdd(dst + 1, m.y);
            atomicAdd(dst + 2, m.z);
            atomicAdd(dst + 3, m.w);
        }
    }
}

// ---------------------------------------------------------------------------
// Dense bi-interaction layer + LeakyReLU + L2 normalize.
//   h = (f + hn) @ W1^T + b1 + (f * hn) @ W2^T + b2
// One wave per row; lane j = output dim (duplicated pair for OUT=32).
// Weight COLUMNS live in per-lane registers (loaded once per wave through a
// coalesced LDS transpose; column copy is 2-way bank aliasing = free).
// Row broadcast via v_readlane (forced with __builtin_amdgcn_readlane so it
// stays off the LDS pipe). Inner loop: 2 readlane + 2 FMA per k, zero LDS.
// ---------------------------------------------------------------------------
template <int OUT>
__global__ __launch_bounds__(256)
void dense_layer_kernel(const float* __restrict__ feat,
                        const float* __restrict__ hneigh,
                        const float* __restrict__ W1,
                        const float* __restrict__ b1,
                        const float* __restrict__ W2,
                        const float* __restrict__ b2,
                        float* __restrict__ out,
                        int nrows) {
    constexpr int IN = 64;
    __shared__ float w1t[IN * OUT];   // [k][j]
    __shared__ float w2t[IN * OUT];

    const int tid = threadIdx.x;
    for (int idx = tid; idx < IN * OUT; idx += blockDim.x) {
        const int j = idx / IN;   // output dim
        const int k = idx % IN;   // input dim
        w1t[k * OUT + j] = W1[idx];
        w2t[k * OUT + j] = W2[idx];
    }
    __syncthreads();

    const int lane = tid & 63;
    const int j    = lane & (OUT - 1);   // duplicated mapping when OUT==32

    // One-time per-lane register copy of weight column j.
    float w1[IN], w2[IN];
#pragma unroll
    for (int k = 0; k < IN; ++k) {
        w1[k] = w1t[k * OUT + j];
        w2[k] = w2t[k * OUT + j];
    }
    const float bias = b1[j] + b2[j];

    const int gwave  = (blockIdx.x * blockDim.x + tid) >> 6;
    const int nwaves = (gridDim.x * blockDim.x) >> 6;

    for (int row = gwave; row < nrows; row += nwaves) {
        const float f  = feat[(size_t)row * IN + lane];
        const float hn = hneigh[(size_t)row * IN + lane];
        const float sv = f + hn;   // sum term
        const float pv = f * hn;   // bi-interaction term

        float acc = bias;
#pragma unroll
        for (int k = 0; k < IN; ++k) {
            const float sk = __uint_as_float(
                __builtin_amdgcn_readlane(__float_as_uint(sv), k));
            const float pk = __uint_as_float(
                __builtin_amdgcn_readlane(__float_as_uint(pv), k));
            acc += sk * w1[k] + pk * w2[k];
        }

        // LeakyReLU
        float hval = (acc >= 0.0f) ? acc : NEG_SLOPE * acc;

        // L2 normalize across the OUT dims of this row
        float sq = (lane < OUT) ? hval * hval : 0.0f;
        float ss = sq;
#pragma unroll
        for (int off = 32; off > 0; off >>= 1) ss += __shfl_xor(ss, off);
        const float nrm   = sqrtf(ss);
        const float scale = 1.0f / fmaxf(nrm, L2_EPS);

        if (lane < OUT) out[(size_t)row * OUT + lane] = hval * scale;
    }
}

// ---------------------------------------------------------------------------
// Final scoring: u/pos/neg gathers over the 160-dim concat embedding,
// two dot products per sample. One wave per sample.
// ---------------------------------------------------------------------------
__global__ __launch_bounds__(256)
void score_kernel(const float* __restrict__ feat0,   // (N,64)
                  const float* __restrict__ feat1,   // (N,64)
                  const float* __restrict__ feat2,   // (N,32)
                  const int* __restrict__ user_ids,
                  const int* __restrict__ pos_ids,
                  const int* __restrict__ neg_ids,
                  float* __restrict__ out) {
    const int lane = threadIdx.x & 63;
    const int i    = (blockIdx.x * blockDim.x + threadIdx.x) >> 6;
    if (i >= BATCH) return;

    const int u  = user_ids[i];
    const int p  = N_USERS + pos_ids[i];
    const int ng = N_USERS + neg_ids[i];

    const float u0 = feat0[(size_t)u * 64 + lane];
    const float p0 = feat0[(size_t)p * 64 + lane];
    const float n0 = feat0[(size_t)ng * 64 + lane];
    const float u1 = feat1[(size_t)u * 64 + lane];
    const float p1 = feat1[(size_t)p * 64 + lane];
    const float n1 = feat1[(size_t)ng * 64 + lane];

    float ap = u0 * p0 + u1 * p1;
    float an = u0 * n0 + u1 * n1;
    if (lane < 32) {
        const float u2 = feat2[(size_t)u * 32 + lane];
        const float p2 = feat2[(size_t)p * 32 + lane];
        const float n2 = feat2[(size_t)ng * 32 + lane];
        ap += u2 * p2;
        an += u2 * n2;
    }
#pragma unroll
    for (int off = 32; off > 0; off >>= 1) {
        ap += __shfl_xor(ap, off);
        an += __shfl_xor(an, off);
    }
    if (lane == 0) {
        out[i]         = ap;
        out[BATCH + i] = an;
    }
}

// ---------------------------------------------------------------------------
extern "C" void kernel_launch(void* const* d_in, const int* in_sizes, int n_in,
                              void* d_out, int out_size, void* d_ws, size_t ws_size,
                              hipStream_t stream) {
    const int*   target       = (const int*)d_in[0];
    const int*   neighbor     = (const int*)d_in[1];
    const float* values       = (const float*)d_in[2];
    const int*   user_ids     = (const int*)d_in[3];
    const int*   pos_item_ids = (const int*)d_in[4];
    const int*   neg_item_ids = (const int*)d_in[5];
    const float* user_embed   = (const float*)d_in[6];
    const float* entity_embed = (const float*)d_in[7];
    const float* W1_0 = (const float*)d_in[8];
    const float* b1_0 = (const float*)d_in[9];
    const float* W2_0 = (const float*)d_in[10];
    const float* b2_0 = (const float*)d_in[11];
    const float* W1_1 = (const float*)d_in[12];
    const float* b1_1 = (const float*)d_in[13];
    const float* W2_1 = (const float*)d_in[14];
    const float* b2_1 = (const float*)d_in[15];

    // Workspace layout (bytes):
    //   feat0  : N*64*4 = 38,400,000
    //   feat1  : N*64*4 = 38,400,000
    //   feat2  : N*32*4 = 19,200,000
    //   hneigh : N*64*4 = 38,400,000      (reused by both layers)
    char* ws = (char*)d_ws;
    float* feat0  = (float*)(ws);
    float* feat1  = (float*)(ws + 38400000);
    float* feat2  = (float*)(ws + 76800000);
    float* hneigh = (float*)(ws + 96000000);

    // all_embed = concat(user_embed, entity_embed)
    hipMemcpyAsync(feat0, user_embed, (size_t)N_USERS * 64 * sizeof(float),
                   hipMemcpyDeviceToDevice, stream);
    hipMemcpyAsync(feat0 + (size_t)N_USERS * 64, entity_embed,
                   (size_t)N_ENTITIES * 64 * sizeof(float),
                   hipMemcpyDeviceToDevice, stream);

    // ---- Layer 0 (64 -> 64) ----
    hipMemsetAsync(hneigh, 0, (size_t)N_NODES * 64 * sizeof(float), stream);
    scatter_kernel<<<2048, 256, 0, stream>>>(feat0, target, neighbor, values,
                                             hneigh, N_EDGES);
    dense_layer_kernel<64><<<2048, 256, 0, stream>>>(feat0, hneigh,
                                                     W1_0, b1_0, W2_0, b2_0,
                                                     feat1, N_NODES);

    // ---- Layer 1 (64 -> 32) ----
    hipMemsetAsync(hneigh, 0, (size_t)N_NODES * 64 * sizeof(float), stream);
    scatter_kernel<<<2048, 256, 0, stream>>>(feat1, target, neighbor, values,
                                             hneigh, N_EDGES);
    dense_layer_kernel<32><<<2048, 256, 0, stream>>>(feat1, hneigh,
                                                     W1_1, b1_1, W2_1, b2_1,
                                                     feat2, N_NODES);

    // ---- Scoring ----
    score_kernel<<<(BATCH * 64) / 256, 256, 0, stream>>>(feat0, feat1, feat2,
                                                         user_ids, pos_item_ids,
                                                         neg_item_ids,
                                                         (float*)d_out);
}

// Round 5
// 859.753 us; speedup vs baseline: 5.2010x; 5.2010x over previous
//
#include <hip/hip_runtime.h>
#include <math.h>

#define N_USERS    50000
#define N_ENTITIES 100000
#define N_NODES    150000
#define EMBED_DIM  64
#define N_EDGES    2400000
#define BATCH      4096
#define NEG_SLOPE  0.01f
#define L2_EPS     1e-12f

#define SCAN_CHUNK 1024
#define SCAN_NBLK  147   // ceil(150000/1024)

// ===========================================================================
// CSR build: histogram -> prefix scan -> permutation fill.
// target/neighbor/values are identical for both layers, so build once.
// ===========================================================================
__global__ __launch_bounds__(256)
void hist_kernel(const int* __restrict__ target, int* __restrict__ cnt, int n) {
    int i = blockIdx.x * blockDim.x + threadIdx.x;
    const int stride = gridDim.x * blockDim.x;
    for (; i < n; i += stride) atomicAdd(&cnt[target[i]], 1);
}

// Per-block exclusive prescan of counts (chunk = 1024 = 256 threads x 4).
__global__ __launch_bounds__(256)
void scan1_kernel(const int* __restrict__ cnt, int* __restrict__ prescan,
                  int* __restrict__ blk_sums, int n) {
    __shared__ int s[256];
    const int b = blockIdx.x, t = threadIdx.x;
    const int idx = b * SCAN_CHUNK + t * 4;
    const int v0 = (idx + 0 < n) ? cnt[idx + 0] : 0;
    const int v1 = (idx + 1 < n) ? cnt[idx + 1] : 0;
    const int v2 = (idx + 2 < n) ? cnt[idx + 2] : 0;
    const int v3 = (idx + 3 < n) ? cnt[idx + 3] : 0;
    s[t] = v0 + v1 + v2 + v3;
    __syncthreads();
#pragma unroll
    for (int off = 1; off < 256; off <<= 1) {
        const int x = (t >= off) ? s[t - off] : 0;
        __syncthreads();
        s[t] += x;
        __syncthreads();
    }
    const int excl = (t == 0) ? 0 : s[t - 1];
    if (idx + 0 < n) prescan[idx + 0] = excl;
    if (idx + 1 < n) prescan[idx + 1] = excl + v0;
    if (idx + 2 < n) prescan[idx + 2] = excl + v0 + v1;
    if (idx + 3 < n) prescan[idx + 3] = excl + v0 + v1 + v2;
    if (t == 255) blk_sums[b] = s[255];
}

// Single-block exclusive scan of the 147 block sums.
__global__ __launch_bounds__(256)
void scan2_kernel(int* __restrict__ blk_sums, int nblk) {
    __shared__ int s[256];
    const int t = threadIdx.x;
    s[t] = (t < nblk) ? blk_sums[t] : 0;
    __syncthreads();
#pragma unroll
    for (int off = 1; off < 256; off <<= 1) {
        const int x = (t >= off) ? s[t - off] : 0;
        __syncthreads();
        s[t] += x;
        __syncthreads();
    }
    if (t < nblk) blk_sums[t] = (t == 0) ? 0 : s[t - 1];
}

// Apply block offsets -> final row_ptr; also init cursor = row_ptr and
// write the sentinel row_ptr[N] = E.
__global__ __launch_bounds__(256)
void scan3_kernel(int* __restrict__ row_ptr, int* __restrict__ cursor,
                  const int* __restrict__ blk_off, int n) {
    const int i = blockIdx.x * blockDim.x + threadIdx.x;
    if (i < n) {
        const int v = row_ptr[i] + blk_off[i >> 10];
        row_ptr[i] = v;
        cursor[i]  = v;
    }
    if (i == 0) row_ptr[n] = N_EDGES;
}

__global__ __launch_bounds__(256)
void fill_kernel(const int* __restrict__ target, const int* __restrict__ neighbor,
                 const float* __restrict__ values, int* __restrict__ cursor,
                 int* __restrict__ col_idx, float* __restrict__ col_val, int n) {
    int i = blockIdx.x * blockDim.x + threadIdx.x;
    const int stride = gridDim.x * blockDim.x;
    for (; i < n; i += stride) {
        const int p = atomicAdd(&cursor[target[i]], 1);
        col_idx[p] = neighbor[i];
        col_val[p] = values[i];
    }
}

// ===========================================================================
// Pull aggregation: h_neigh[r] = sum over in-edges of feat[nbr]*v.
// One wave per row, lane = dim. Register accumulation, 4-edge unroll for
// memory-level parallelism. One coalesced 256B store per row, NO f32 atomics.
// ===========================================================================
__global__ __launch_bounds__(256)
void pull_kernel(const float* __restrict__ feat,
                 const int*   __restrict__ row_ptr,
                 const int*   __restrict__ col_idx,
                 const float* __restrict__ col_val,
                 float*       __restrict__ hneigh,
                 int nrows) {
    const int lane   = threadIdx.x & 63;
    const int gwave  = (blockIdx.x * blockDim.x + threadIdx.x) >> 6;
    const int nwaves = (gridDim.x * blockDim.x) >> 6;

    for (int r = gwave; r < nrows; r += nwaves) {
        const int s = row_ptr[r];
        const int e = row_ptr[r + 1];
        float a0 = 0.f, a1 = 0.f, a2 = 0.f, a3 = 0.f;
        int i = s;
        for (; i + 3 < e; i += 4) {
            const int n0 = col_idx[i + 0], n1 = col_idx[i + 1];
            const int n2 = col_idx[i + 2], n3 = col_idx[i + 3];
            const float v0 = col_val[i + 0], v1 = col_val[i + 1];
            const float v2 = col_val[i + 2], v3 = col_val[i + 3];
            a0 += feat[(size_t)n0 * 64 + lane] * v0;
            a1 += feat[(size_t)n1 * 64 + lane] * v1;
            a2 += feat[(size_t)n2 * 64 + lane] * v2;
            a3 += feat[(size_t)n3 * 64 + lane] * v3;
        }
        for (; i < e; ++i)
            a0 += feat[(size_t)col_idx[i] * 64 + lane] * col_val[i];
        hneigh[(size_t)r * 64 + lane] = (a0 + a1) + (a2 + a3);
    }
}

// ===========================================================================
// Dense bi-interaction layer + LeakyReLU + L2 normalize.
//   h = (f + hn) @ W1^T + b1 + (f * hn) @ W2^T + b2
// One wave per row; lane j = output dim (duplicated pair for OUT=32).
// Weight columns in per-lane registers; broadcast via v_readlane.
// ===========================================================================
template <int OUT>
__global__ __launch_bounds__(256)
void dense_layer_kernel(const float* __restrict__ feat,
                        const float* __restrict__ hneigh,
                        const float* __restrict__ W1,
                        const float* __restrict__ b1,
                        const float* __restrict__ W2,
                        const float* __restrict__ b2,
                        float* __restrict__ out,
                        int nrows) {
    constexpr int IN = 64;
    __shared__ float w1t[IN * OUT];   // [k][j]
    __shared__ float w2t[IN * OUT];

    const int tid = threadIdx.x;
    for (int idx = tid; idx < IN * OUT; idx += blockDim.x) {
        const int j = idx / IN;   // output dim
        const int k = idx % IN;   // input dim
        w1t[k * OUT + j] = W1[idx];
        w2t[k * OUT + j] = W2[idx];
    }
    __syncthreads();

    const int lane = tid & 63;
    const int j    = lane & (OUT - 1);

    float w1[IN], w2[IN];
#pragma unroll
    for (int k = 0; k < IN; ++k) {
        w1[k] = w1t[k * OUT + j];
        w2[k] = w2t[k * OUT + j];
    }
    const float bias = b1[j] + b2[j];

    const int gwave  = (blockIdx.x * blockDim.x + tid) >> 6;
    const int nwaves = (gridDim.x * blockDim.x) >> 6;

    for (int row = gwave; row < nrows; row += nwaves) {
        const float f  = feat[(size_t)row * IN + lane];
        const float hn = hneigh[(size_t)row * IN + lane];
        const float sv = f + hn;
        const float pv = f * hn;

        float acc = bias;
#pragma unroll
        for (int k = 0; k < IN; ++k) {
            const float sk = __uint_as_float(
                __builtin_amdgcn_readlane(__float_as_uint(sv), k));
            const float pk = __uint_as_float(
                __builtin_amdgcn_readlane(__float_as_uint(pv), k));
            acc += sk * w1[k] + pk * w2[k];
        }

        float hval = (acc >= 0.0f) ? acc : NEG_SLOPE * acc;

        float sq = (lane < OUT) ? hval * hval : 0.0f;
        float ss = sq;
#pragma unroll
        for (int off = 32; off > 0; off >>= 1) ss += __shfl_xor(ss, off);
        const float nrm   = sqrtf(ss);
        const float scale = 1.0f / fmaxf(nrm, L2_EPS);

        if (lane < OUT) out[(size_t)row * OUT + lane] = hval * scale;
    }
}

// ===========================================================================
// Final scoring. One wave per sample.
// ===========================================================================
__global__ __launch_bounds__(256)
void score_kernel(const float* __restrict__ feat0,
                  const float* __restrict__ feat1,
                  const float* __restrict__ feat2,
                  const int* __restrict__ user_ids,
                  const int* __restrict__ pos_ids,
                  const int* __restrict__ neg_ids,
                  float* __restrict__ out) {
    const int lane = threadIdx.x & 63;
    const int i    = (blockIdx.x * blockDim.x + threadIdx.x) >> 6;
    if (i >= BATCH) return;

    const int u  = user_ids[i];
    const int p  = N_USERS + pos_ids[i];
    const int ng = N_USERS + neg_ids[i];

    const float u0 = feat0[(size_t)u * 64 + lane];
    const float p0 = feat0[(size_t)p * 64 + lane];
    const float n0 = feat0[(size_t)ng * 64 + lane];
    const float u1 = feat1[(size_t)u * 64 + lane];
    const float p1 = feat1[(size_t)p * 64 + lane];
    const float n1 = feat1[(size_t)ng * 64 + lane];

    float ap = u0 * p0 + u1 * p1;
    float an = u0 * n0 + u1 * n1;
    if (lane < 32) {
        const float u2 = feat2[(size_t)u * 32 + lane];
        const float p2 = feat2[(size_t)p * 32 + lane];
        const float n2 = feat2[(size_t)ng * 32 + lane];
        ap += u2 * p2;
        an += u2 * n2;
    }
#pragma unroll
    for (int off = 32; off > 0; off >>= 1) {
        ap += __shfl_xor(ap, off);
        an += __shfl_xor(an, off);
    }
    if (lane == 0) {
        out[i]         = ap;
        out[BATCH + i] = an;
    }
}

// ===========================================================================
extern "C" void kernel_launch(void* const* d_in, const int* in_sizes, int n_in,
                              void* d_out, int out_size, void* d_ws, size_t ws_size,
                              hipStream_t stream) {
    const int*   target       = (const int*)d_in[0];
    const int*   neighbor     = (const int*)d_in[1];
    const float* values       = (const float*)d_in[2];
    const int*   user_ids     = (const int*)d_in[3];
    const int*   pos_item_ids = (const int*)d_in[4];
    const int*   neg_item_ids = (const int*)d_in[5];
    const float* user_embed   = (const float*)d_in[6];
    const float* entity_embed = (const float*)d_in[7];
    const float* W1_0 = (const float*)d_in[8];
    const float* b1_0 = (const float*)d_in[9];
    const float* W2_0 = (const float*)d_in[10];
    const float* b2_0 = (const float*)d_in[11];
    const float* W1_1 = (const float*)d_in[12];
    const float* b1_1 = (const float*)d_in[13];
    const float* W2_1 = (const float*)d_in[14];
    const float* b2_1 = (const float*)d_in[15];

    // Workspace layout (bytes):
    //   feat0   @ 0           : 38,400,000
    //   feat1   @ 38,400,000  : 38,400,000
    //   feat2   @ 76,800,000  : 19,200,000   (also hosts col_idx/col_val
    //                                         during CSR+pull phase; feat2 is
    //                                         only written by the final dense)
    //   hneigh  @ 96,000,000  : 38,400,000
    //   row_ptr @ 134,400,000 :    600,064   (150001 ints)
    //   cursor  @ 135,000,064 :    600,000   (doubles as histogram counts)
    //   blk_sums@ 135,600,064 :      1,024
    char* ws = (char*)d_ws;
    float* feat0   = (float*)(ws);
    float* feat1   = (float*)(ws + 38400000);
    float* feat2   = (float*)(ws + 76800000);
    int*   col_idx = (int*)  (ws + 76800000);            // 9.6 MB
    float* col_val = (float*)(ws + 86400000);            // 9.6 MB
    float* hneigh  = (float*)(ws + 96000000);
    int*   row_ptr = (int*)  (ws + 134400000);
    int*   cursor  = (int*)  (ws + 135000064);
    int*   blk_sums= (int*)  (ws + 135600064);

    // all_embed = concat(user_embed, entity_embed)
    hipMemcpyAsync(feat0, user_embed, (size_t)N_USERS * 64 * sizeof(float),
                   hipMemcpyDeviceToDevice, stream);
    hipMemcpyAsync(feat0 + (size_t)N_USERS * 64, entity_embed,
                   (size_t)N_ENTITIES * 64 * sizeof(float),
                   hipMemcpyDeviceToDevice, stream);

    // ---- CSR build (once; edges identical for both layers) ----
    hipMemsetAsync(cursor, 0, (size_t)N_NODES * sizeof(int), stream);
    hist_kernel <<<2048, 256, 0, stream>>>(target, cursor, N_EDGES);
    scan1_kernel<<<SCAN_NBLK, 256, 0, stream>>>(cursor, row_ptr, blk_sums, N_NODES);
    scan2_kernel<<<1, 256, 0, stream>>>(blk_sums, SCAN_NBLK);
    scan3_kernel<<<(N_NODES + 255) / 256, 256, 0, stream>>>(row_ptr, cursor,
                                                            blk_sums, N_NODES);
    fill_kernel <<<2048, 256, 0, stream>>>(target, neighbor, values, cursor,
                                           col_idx, col_val, N_EDGES);

    // ---- Layer 0 (64 -> 64) ----
    pull_kernel<<<2048, 256, 0, stream>>>(feat0, row_ptr, col_idx, col_val,
                                          hneigh, N_NODES);
    dense_layer_kernel<64><<<2048, 256, 0, stream>>>(feat0, hneigh,
                                                     W1_0, b1_0, W2_0, b2_0,
                                                     feat1, N_NODES);

    // ---- Layer 1 (64 -> 32) ----
    pull_kernel<<<2048, 256, 0, stream>>>(feat1, row_ptr, col_idx, col_val,
                                          hneigh, N_NODES);
    dense_layer_kernel<32><<<2048, 256, 0, stream>>>(feat1, hneigh,
                                                     W1_1, b1_1, W2_1, b2_1,
                                                     feat2, N_NODES);

    // ---- Scoring ----
    score_kernel<<<(BATCH * 64) / 256, 256, 0, stream>>>(feat0, feat1, feat2,
                                                         user_ids, pos_item_ids,
                                                         neg_item_ids,
                                                         (float*)d_out);
}

// Round 8
// 783.800 us; speedup vs baseline: 5.7050x; 1.0969x over previous
//
#include <hip/hip_runtime.h>
#include <math.h>

#define N_USERS    50000
#define N_ENTITIES 100000
#define N_NODES    150000
#define EMBED_DIM  64
#define N_EDGES    2400000
#define BATCH      4096
#define NEG_SLOPE  0.01f
#define L2_EPS     1e-12f

#define SCAN_CHUNK 1024
#define SCAN_NBLK  147   // ceil(150000/1024)

// Row source for layer-0 (no materialized concat): branch user/entity table.
template <bool SPLIT>
__device__ __forceinline__ const float* node_row(const float* __restrict__ feat,
                                                 const float* __restrict__ ue,
                                                 const float* __restrict__ ee,
                                                 int node) {
    if (SPLIT)
        return (node < N_USERS) ? ue + (size_t)node * 64
                                : ee + (size_t)(node - N_USERS) * 64;
    return feat + (size_t)node * 64;
}

// ===========================================================================
// CSR build: histogram -> prefix scan -> permutation fill (packed int2).
// ===========================================================================
__global__ __launch_bounds__(256)
void hist_kernel(const int* __restrict__ target, int* __restrict__ cnt, int n) {
    int i = blockIdx.x * blockDim.x + threadIdx.x;
    const int stride = gridDim.x * blockDim.x;
    for (; i < n; i += stride) atomicAdd(&cnt[target[i]], 1);
}

__global__ __launch_bounds__(256)
void scan1_kernel(const int* __restrict__ cnt, int* __restrict__ prescan,
                  int* __restrict__ blk_sums, int n) {
    __shared__ int s[256];
    const int b = blockIdx.x, t = threadIdx.x;
    const int idx = b * SCAN_CHUNK + t * 4;
    const int v0 = (idx + 0 < n) ? cnt[idx + 0] : 0;
    const int v1 = (idx + 1 < n) ? cnt[idx + 1] : 0;
    const int v2 = (idx + 2 < n) ? cnt[idx + 2] : 0;
    const int v3 = (idx + 3 < n) ? cnt[idx + 3] : 0;
    s[t] = v0 + v1 + v2 + v3;
    __syncthreads();
#pragma unroll
    for (int off = 1; off < 256; off <<= 1) {
        const int x = (t >= off) ? s[t - off] : 0;
        __syncthreads();
        s[t] += x;
        __syncthreads();
    }
    const int excl = (t == 0) ? 0 : s[t - 1];
    if (idx + 0 < n) prescan[idx + 0] = excl;
    if (idx + 1 < n) prescan[idx + 1] = excl + v0;
    if (idx + 2 < n) prescan[idx + 2] = excl + v0 + v1;
    if (idx + 3 < n) prescan[idx + 3] = excl + v0 + v1 + v2;
    if (t == 255) blk_sums[b] = s[255];
}

__global__ __launch_bounds__(256)
void scan2_kernel(int* __restrict__ blk_sums, int nblk) {
    __shared__ int s[256];
    const int t = threadIdx.x;
    s[t] = (t < nblk) ? blk_sums[t] : 0;
    __syncthreads();
#pragma unroll
    for (int off = 1; off < 256; off <<= 1) {
        const int x = (t >= off) ? s[t - off] : 0;
        __syncthreads();
        s[t] += x;
        __syncthreads();
    }
    if (t < nblk) blk_sums[t] = (t == 0) ? 0 : s[t - 1];
}

__global__ __launch_bounds__(256)
void scan3_kernel(int* __restrict__ row_ptr, int* __restrict__ cursor,
                  const int* __restrict__ blk_off, int n) {
    const int i = blockIdx.x * blockDim.x + threadIdx.x;
    if (i < n) {
        const int v = row_ptr[i] + blk_off[i >> 10];
        row_ptr[i] = v;
        cursor[i]  = v;
    }
    if (i == 0) row_ptr[n] = N_EDGES;
}

// Packed fill: ONE 8B scattered store per edge (nbr, value-bits).
__global__ __launch_bounds__(256)
void fill_kernel(const int* __restrict__ target, const int* __restrict__ neighbor,
                 const float* __restrict__ values, int* __restrict__ cursor,
                 int2* __restrict__ col, int n) {
    int i = blockIdx.x * blockDim.x + threadIdx.x;
    const int stride = gridDim.x * blockDim.x;
    for (; i < n; i += stride) {
        const int p = atomicAdd(&cursor[target[i]], 1);
        col[p] = make_int2(neighbor[i], __float_as_int(values[i]));
    }
}

// ===========================================================================
// Pull aggregation: h_neigh[r] = sum over in-edges of feat[nbr]*v.
// One wave per row, lane = dim; packed int2 edge reads (wave-uniform
// broadcast); 4-edge unroll for MLP; one coalesced 256B store; no f32 atomics.
// ===========================================================================
template <bool SPLIT>
__global__ __launch_bounds__(256)
void pull_kernel(const float* __restrict__ feat,
                 const float* __restrict__ ue,
                 const float* __restrict__ ee,
                 const int*   __restrict__ row_ptr,
                 const int2*  __restrict__ col,
                 float*       __restrict__ hneigh,
                 int nrows) {
    const int lane   = threadIdx.x & 63;
    const int gwave  = (blockIdx.x * blockDim.x + threadIdx.x) >> 6;
    const int nwaves = (gridDim.x * blockDim.x) >> 6;

    for (int r = gwave; r < nrows; r += nwaves) {
        const int s = row_ptr[r];
        const int e = row_ptr[r + 1];
        float a0 = 0.f, a1 = 0.f, a2 = 0.f, a3 = 0.f;
        int i = s;
        for (; i + 3 < e; i += 4) {
            const int2 c0 = col[i + 0], c1 = col[i + 1];
            const int2 c2 = col[i + 2], c3 = col[i + 3];
            a0 += node_row<SPLIT>(feat, ue, ee, c0.x)[lane] * __int_as_float(c0.y);
            a1 += node_row<SPLIT>(feat, ue, ee, c1.x)[lane] * __int_as_float(c1.y);
            a2 += node_row<SPLIT>(feat, ue, ee, c2.x)[lane] * __int_as_float(c2.y);
            a3 += node_row<SPLIT>(feat, ue, ee, c3.x)[lane] * __int_as_float(c3.y);
        }
        for (; i < e; ++i) {
            const int2 c = col[i];
            a0 += node_row<SPLIT>(feat, ue, ee, c.x)[lane] * __int_as_float(c.y);
        }
        hneigh[(size_t)r * 64 + lane] = (a0 + a1) + (a2 + a3);
    }
}

// ===========================================================================
// Dense bi-interaction layer + LeakyReLU + L2 normalize.
//   h = (f + hn) @ W1^T + b1 + (f * hn) @ W2^T + b2
// One wave per row; lane j = output dim (duplicated pair for OUT=32).
// Weight columns in per-lane registers; broadcast via v_readlane.
// ===========================================================================
template <int OUT, bool SPLIT>
__global__ __launch_bounds__(256)
void dense_layer_kernel(const float* __restrict__ feat,
                        const float* __restrict__ ue,
                        const float* __restrict__ ee,
                        const float* __restrict__ hneigh,
                        const float* __restrict__ W1,
                        const float* __restrict__ b1,
                        const float* __restrict__ W2,
                        const float* __restrict__ b2,
                        float* __restrict__ out,
                        int nrows) {
    constexpr int IN = 64;
    __shared__ float w1t[IN * OUT];   // [k][j]
    __shared__ float w2t[IN * OUT];

    const int tid = threadIdx.x;
    for (int idx = tid; idx < IN * OUT; idx += blockDim.x) {
        const int j = idx / IN;
        const int k = idx % IN;
        w1t[k * OUT + j] = W1[idx];
        w2t[k * OUT + j] = W2[idx];
    }
    __syncthreads();

    const int lane = tid & 63;
    const int j    = lane & (OUT - 1);

    float w1[IN], w2[IN];
#pragma unroll
    for (int k = 0; k < IN; ++k) {
        w1[k] = w1t[k * OUT + j];
        w2[k] = w2t[k * OUT + j];
    }
    const float bias = b1[j] + b2[j];

    const int gwave  = (blockIdx.x * blockDim.x + tid) >> 6;
    const int nwaves = (gridDim.x * blockDim.x) >> 6;

    for (int row = gwave; row < nrows; row += nwaves) {
        const float f  = node_row<SPLIT>(feat, ue, ee, row)[lane];
        const float hn = hneigh[(size_t)row * IN + lane];
        const float sv = f + hn;
        const float pv = f * hn;

        float acc = bias;
#pragma unroll
        for (int k = 0; k < IN; ++k) {
            const float sk = __uint_as_float(
                __builtin_amdgcn_readlane(__float_as_uint(sv), k));
            const float pk = __uint_as_float(
                __builtin_amdgcn_readlane(__float_as_uint(pv), k));
            acc += sk * w1[k] + pk * w2[k];
        }

        float hval = (acc >= 0.0f) ? acc : NEG_SLOPE * acc;

        float sq = (lane < OUT) ? hval * hval : 0.0f;
        float ss = sq;
#pragma unroll
        for (int off = 32; off > 0; off >>= 1) ss += __shfl_xor(ss, off);
        const float nrm   = sqrtf(ss);
        const float scale = 1.0f / fmaxf(nrm, L2_EPS);

        if (lane < OUT) out[(size_t)row * OUT + lane] = hval * scale;
    }
}

// ===========================================================================
// Final scoring. One wave per sample. Layer-0 features read straight from
// the user/entity tables (u is always a user; pos/neg always entities).
// ===========================================================================
__global__ __launch_bounds__(256)
void score_kernel(const float* __restrict__ ue,     // (N_USERS,64)
                  const float* __restrict__ ee,     // (N_ENTITIES,64)
                  const float* __restrict__ feat1,  // (N,64)
                  const float* __restrict__ feat2,  // (N,32)
                  const int* __restrict__ user_ids,
                  const int* __restrict__ pos_ids,
                  const int* __restrict__ neg_ids,
                  float* __restrict__ out) {
    const int lane = threadIdx.x & 63;
    const int i    = (blockIdx.x * blockDim.x + threadIdx.x) >> 6;
    if (i >= BATCH) return;

    const int uid = user_ids[i];
    const int pid = pos_ids[i];
    const int nid = neg_ids[i];
    const int u  = uid;                 // node index of user
    const int p  = N_USERS + pid;
    const int ng = N_USERS + nid;

    const float u0 = ue[(size_t)uid * 64 + lane];
    const float p0 = ee[(size_t)pid * 64 + lane];
    const float n0 = ee[(size_t)nid * 64 + lane];
    const float u1 = feat1[(size_t)u * 64 + lane];
    const float p1 = feat1[(size_t)p * 64 + lane];
    const float n1 = feat1[(size_t)ng * 64 + lane];

    float ap = u0 * p0 + u1 * p1;
    float an = u0 * n0 + u1 * n1;
    if (lane < 32) {
        const float u2 = feat2[(size_t)u * 32 + lane];
        const float p2 = feat2[(size_t)p * 32 + lane];
        const float n2 = feat2[(size_t)ng * 32 + lane];
        ap += u2 * p2;
        an += u2 * n2;
    }
#pragma unroll
    for (int off = 32; off > 0; off >>= 1) {
        ap += __shfl_xor(ap, off);
        an += __shfl_xor(an, off);
    }
    if (lane == 0) {
        out[i]         = ap;
        out[BATCH + i] = an;
    }
}

// ===========================================================================
extern "C" void kernel_launch(void* const* d_in, const int* in_sizes, int n_in,
                              void* d_out, int out_size, void* d_ws, size_t ws_size,
                              hipStream_t stream) {
    const int*   target       = (const int*)d_in[0];
    const int*   neighbor     = (const int*)d_in[1];
    const float* values       = (const float*)d_in[2];
    const int*   user_ids     = (const int*)d_in[3];
    const int*   pos_item_ids = (const int*)d_in[4];
    const int*   neg_item_ids = (const int*)d_in[5];
    const float* user_embed   = (const float*)d_in[6];
    const float* entity_embed = (const float*)d_in[7];
    const float* W1_0 = (const float*)d_in[8];
    const float* b1_0 = (const float*)d_in[9];
    const float* W2_0 = (const float*)d_in[10];
    const float* b2_0 = (const float*)d_in[11];
    const float* W1_1 = (const float*)d_in[12];
    const float* b1_1 = (const float*)d_in[13];
    const float* W2_1 = (const float*)d_in[14];
    const float* b2_1 = (const float*)d_in[15];

    // Workspace layout (bytes):
    //   (unused)@ 0           : 38,400,000   (former feat0 slot)
    //   feat1   @ 38,400,000  : 38,400,000
    //   feat2   @ 76,800,000  : 19,200,000   (hosts packed col during
    //                                         CSR+pull; feat2 written last)
    //   hneigh  @ 96,000,000  : 38,400,000
    //   row_ptr @ 134,400,000 :    600,064   (150001 ints)
    //   cursor  @ 135,000,064 :    600,000   (doubles as histogram counts)
    //   blk_sums@ 135,600,064 :      1,024
    char* ws = (char*)d_ws;
    float* feat1   = (float*)(ws + 38400000);
    float* feat2   = (float*)(ws + 76800000);
    int2*  col     = (int2*) (ws + 76800000);   // 2.4M x 8B = 19.2 MB
    float* hneigh  = (float*)(ws + 96000000);
    int*   row_ptr = (int*)  (ws + 134400000);
    int*   cursor  = (int*)  (ws + 135000064);
    int*   blk_sums= (int*)  (ws + 135600064);

    // ---- CSR build (once; edges identical for both layers) ----
    hipMemsetAsync(cursor, 0, (size_t)N_NODES * sizeof(int), stream);
    hist_kernel <<<2048, 256, 0, stream>>>(target, cursor, N_EDGES);
    scan1_kernel<<<SCAN_NBLK, 256, 0, stream>>>(cursor, row_ptr, blk_sums, N_NODES);
    scan2_kernel<<<1, 256, 0, stream>>>(blk_sums, SCAN_NBLK);
    scan3_kernel<<<(N_NODES + 255) / 256, 256, 0, stream>>>(row_ptr, cursor,
                                                            blk_sums, N_NODES);
    fill_kernel <<<2048, 256, 0, stream>>>(target, neighbor, values, cursor,
                                           col, N_EDGES);

    // ---- Layer 0 (64 -> 64), reading the split embedding tables ----
    pull_kernel<true><<<2048, 256, 0, stream>>>(nullptr, user_embed, entity_embed,
                                                row_ptr, col, hneigh, N_NODES);
    dense_layer_kernel<64, true><<<2048, 256, 0, stream>>>(
        nullptr, user_embed, entity_embed, hneigh,
        W1_0, b1_0, W2_0, b2_0, feat1, N_NODES);

    // ---- Layer 1 (64 -> 32) ----
    pull_kernel<false><<<2048, 256, 0, stream>>>(feat1, nullptr, nullptr,
                                                 row_ptr, col, hneigh, N_NODES);
    dense_layer_kernel<32, false><<<2048, 256, 0, stream>>>(
        feat1, nullptr, nullptr, hneigh,
        W1_1, b1_1, W2_1, b2_1, feat2, N_NODES);

    // ---- Scoring ----
    score_kernel<<<(BATCH * 64) / 256, 256, 0, stream>>>(user_embed, entity_embed,
                                                         feat1, feat2,
                                                         user_ids, pos_item_ids,
                                                         neg_item_ids,
                                                         (float*)d_out);
}

// Round 9
// 763.661 us; speedup vs baseline: 5.8554x; 1.0264x over previous
//
#include <hip/hip_runtime.h>
#include <math.h>

#define N_USERS    50000
#define N_ENTITIES 100000
#define N_NODES    150000
#define EMBED_DIM  64
#define N_EDGES    2400000
#define BATCH      4096
#define NEG_SLOPE  0.01f
#define L2_EPS     1e-12f

#define SCAN_CHUNK 1024
#define SCAN_NBLK  147   // ceil(150000/1024)

// Row source for layer-0 (no materialized concat): branch user/entity table.
template <bool SPLIT>
__device__ __forceinline__ const float* node_row(const float* __restrict__ feat,
                                                 const float* __restrict__ ue,
                                                 const float* __restrict__ ee,
                                                 int node) {
    if (SPLIT)
        return (node < N_USERS) ? ue + (size_t)node * 64
                                : ee + (size_t)(node - N_USERS) * 64;
    return feat + (size_t)node * 64;
}

// ===========================================================================
// CSR build: histogram -> prefix scan -> permutation fill (packed int2).
// ===========================================================================
__global__ __launch_bounds__(256)
void hist_kernel(const int* __restrict__ target, int* __restrict__ cnt, int n) {
    int i = blockIdx.x * blockDim.x + threadIdx.x;
    const int stride = gridDim.x * blockDim.x;
    for (; i < n; i += stride) atomicAdd(&cnt[target[i]], 1);
}

__global__ __launch_bounds__(256)
void scan1_kernel(const int* __restrict__ cnt, int* __restrict__ prescan,
                  int* __restrict__ blk_sums, int n) {
    __shared__ int s[256];
    const int b = blockIdx.x, t = threadIdx.x;
    const int idx = b * SCAN_CHUNK + t * 4;
    const int v0 = (idx + 0 < n) ? cnt[idx + 0] : 0;
    const int v1 = (idx + 1 < n) ? cnt[idx + 1] : 0;
    const int v2 = (idx + 2 < n) ? cnt[idx + 2] : 0;
    const int v3 = (idx + 3 < n) ? cnt[idx + 3] : 0;
    s[t] = v0 + v1 + v2 + v3;
    __syncthreads();
#pragma unroll
    for (int off = 1; off < 256; off <<= 1) {
        const int x = (t >= off) ? s[t - off] : 0;
        __syncthreads();
        s[t] += x;
        __syncthreads();
    }
    const int excl = (t == 0) ? 0 : s[t - 1];
    if (idx + 0 < n) prescan[idx + 0] = excl;
    if (idx + 1 < n) prescan[idx + 1] = excl + v0;
    if (idx + 2 < n) prescan[idx + 2] = excl + v0 + v1;
    if (idx + 3 < n) prescan[idx + 3] = excl + v0 + v1 + v2;
    if (t == 255) blk_sums[b] = s[255];
}

__global__ __launch_bounds__(256)
void scan2_kernel(int* __restrict__ blk_sums, int nblk) {
    __shared__ int s[256];
    const int t = threadIdx.x;
    s[t] = (t < nblk) ? blk_sums[t] : 0;
    __syncthreads();
#pragma unroll
    for (int off = 1; off < 256; off <<= 1) {
        const int x = (t >= off) ? s[t - off] : 0;
        __syncthreads();
        s[t] += x;
        __syncthreads();
    }
    if (t < nblk) blk_sums[t] = (t == 0) ? 0 : s[t - 1];
}

__global__ __launch_bounds__(256)
void scan3_kernel(int* __restrict__ row_ptr, int* __restrict__ cursor,
                  const int* __restrict__ blk_off, int n) {
    const int i = blockIdx.x * blockDim.x + threadIdx.x;
    if (i < n) {
        const int v = row_ptr[i] + blk_off[i >> 10];
        row_ptr[i] = v;
        cursor[i]  = v;
    }
    if (i == 0) row_ptr[n] = N_EDGES;
}

// Packed fill: ONE 8B scattered store per edge (nbr, value-bits).
__global__ __launch_bounds__(256)
void fill_kernel(const int* __restrict__ target, const int* __restrict__ neighbor,
                 const float* __restrict__ values, int* __restrict__ cursor,
                 int2* __restrict__ col, int n) {
    int i = blockIdx.x * blockDim.x + threadIdx.x;
    const int stride = gridDim.x * blockDim.x;
    for (; i < n; i += stride) {
        const int p = atomicAdd(&cursor[target[i]], 1);
        col[p] = make_int2(neighbor[i], __float_as_int(values[i]));
    }
}

// ===========================================================================
// Pull aggregation: h_neigh[r] = sum over in-edges of feat[nbr]*v.
// One wave per row, lane = dim; packed int2 edge reads (wave-uniform
// broadcast); 4-edge unroll for MLP; one coalesced 256B store; no f32 atomics.
// ===========================================================================
template <bool SPLIT>
__global__ __launch_bounds__(256)
void pull_kernel(const float* __restrict__ feat,
                 const float* __restrict__ ue,
                 const float* __restrict__ ee,
                 const int*   __restrict__ row_ptr,
                 const int2*  __restrict__ col,
                 float*       __restrict__ hneigh,
                 int nrows) {
    const int lane   = threadIdx.x & 63;
    const int gwave  = (blockIdx.x * blockDim.x + threadIdx.x) >> 6;
    const int nwaves = (gridDim.x * blockDim.x) >> 6;

    for (int r = gwave; r < nrows; r += nwaves) {
        const int s = row_ptr[r];
        const int e = row_ptr[r + 1];
        float a0 = 0.f, a1 = 0.f, a2 = 0.f, a3 = 0.f;
        int i = s;
        for (; i + 3 < e; i += 4) {
            const int2 c0 = col[i + 0], c1 = col[i + 1];
            const int2 c2 = col[i + 2], c3 = col[i + 3];
            a0 += node_row<SPLIT>(feat, ue, ee, c0.x)[lane] * __int_as_float(c0.y);
            a1 += node_row<SPLIT>(feat, ue, ee, c1.x)[lane] * __int_as_float(c1.y);
            a2 += node_row<SPLIT>(feat, ue, ee, c2.x)[lane] * __int_as_float(c2.y);
            a3 += node_row<SPLIT>(feat, ue, ee, c3.x)[lane] * __int_as_float(c3.y);
        }
        for (; i < e; ++i) {
            const int2 c = col[i];
            a0 += node_row<SPLIT>(feat, ue, ee, c.x)[lane] * __int_as_float(c.y);
        }
        hneigh[(size_t)r * 64 + lane] = (a0 + a1) + (a2 + a3);
    }
}

// ===========================================================================
// Dense bi-interaction layer + LeakyReLU + L2 normalize.
//   h = (f + hn) @ W1^T + b1 + (f * hn) @ W2^T + b2
// One wave per row; lane j = output dim (duplicated pair for OUT=32).
// __launch_bounds__(256, 1): VGPR cap 512 so the per-lane weight COLUMNS
// (128 floats) stay in registers -> inner loop is 2 readlane + 2 FMA, no LDS.
// LDS transpose stride padded to OUT+1 (kills the 64-way staging-write
// conflict measured at 1.6e7 in round 8). Row loop software-pipelined.
// ===========================================================================
template <int OUT, bool SPLIT>
__global__ __launch_bounds__(256, 1)
void dense_layer_kernel(const float* __restrict__ feat,
                        const float* __restrict__ ue,
                        const float* __restrict__ ee,
                        const float* __restrict__ hneigh,
                        const float* __restrict__ W1,
                        const float* __restrict__ b1,
                        const float* __restrict__ W2,
                        const float* __restrict__ b2,
                        float* __restrict__ out,
                        int nrows) {
    constexpr int IN  = 64;
    constexpr int LDP = OUT + 1;          // padded stride: banks spread
    __shared__ float w1t[IN * LDP];       // [k][j] transposed, padded
    __shared__ float w2t[IN * LDP];

    const int tid = threadIdx.x;
    for (int idx = tid; idx < IN * OUT; idx += blockDim.x) {
        const int j = idx / IN;
        const int k = idx % IN;
        w1t[k * LDP + j] = W1[idx];
        w2t[k * LDP + j] = W2[idx];
    }
    __syncthreads();

    const int lane = tid & 63;
    const int j    = lane & (OUT - 1);

    // Per-lane register copy of weight column j (128 VGPRs).
    float w1[IN], w2[IN];
#pragma unroll
    for (int k = 0; k < IN; ++k) {
        w1[k] = w1t[k * LDP + j];
        w2[k] = w2t[k * LDP + j];
    }
    const float bias = b1[j] + b2[j];

    const int gwave  = (blockIdx.x * blockDim.x + tid) >> 6;
    const int nwaves = (gridDim.x * blockDim.x) >> 6;

    int row = gwave;
    if (row < nrows) {
        float f  = node_row<SPLIT>(feat, ue, ee, row)[lane];
        float hn = hneigh[(size_t)row * IN + lane];
        while (true) {
            const int nrow = row + nwaves;
            float fN, hnN;
            if (nrow < nrows) {               // prefetch next row
                fN  = node_row<SPLIT>(feat, ue, ee, nrow)[lane];
                hnN = hneigh[(size_t)nrow * IN + lane];
            }

            const float sv = f + hn;
            const float pv = f * hn;

            float acc = bias;
#pragma unroll
            for (int k = 0; k < IN; ++k) {
                const float sk = __uint_as_float(
                    __builtin_amdgcn_readlane(__float_as_uint(sv), k));
                const float pk = __uint_as_float(
                    __builtin_amdgcn_readlane(__float_as_uint(pv), k));
                acc += sk * w1[k] + pk * w2[k];
            }

            float hval = (acc >= 0.0f) ? acc : NEG_SLOPE * acc;

            float sq = (lane < OUT) ? hval * hval : 0.0f;
            float ss = sq;
#pragma unroll
            for (int off = 32; off > 0; off >>= 1) ss += __shfl_xor(ss, off);
            const float nrm   = sqrtf(ss);
            const float scale = 1.0f / fmaxf(nrm, L2_EPS);

            if (lane < OUT) out[(size_t)row * OUT + lane] = hval * scale;

            if (nrow >= nrows) break;
            row = nrow; f = fN; hn = hnN;
        }
    }
}

// ===========================================================================
// Final scoring. One wave per sample. Layer-0 features read straight from
// the user/entity tables (u is always a user; pos/neg always entities).
// ===========================================================================
__global__ __launch_bounds__(256)
void score_kernel(const float* __restrict__ ue,     // (N_USERS,64)
                  const float* __restrict__ ee,     // (N_ENTITIES,64)
                  const float* __restrict__ feat1,  // (N,64)
                  const float* __restrict__ feat2,  // (N,32)
                  const int* __restrict__ user_ids,
                  const int* __restrict__ pos_ids,
                  const int* __restrict__ neg_ids,
                  float* __restrict__ out) {
    const int lane = threadIdx.x & 63;
    const int i    = (blockIdx.x * blockDim.x + threadIdx.x) >> 6;
    if (i >= BATCH) return;

    const int uid = user_ids[i];
    const int pid = pos_ids[i];
    const int nid = neg_ids[i];
    const int u  = uid;                 // node index of user
    const int p  = N_USERS + pid;
    const int ng = N_USERS + nid;

    const float u0 = ue[(size_t)uid * 64 + lane];
    const float p0 = ee[(size_t)pid * 64 + lane];
    const float n0 = ee[(size_t)nid * 64 + lane];
    const float u1 = feat1[(size_t)u * 64 + lane];
    const float p1 = feat1[(size_t)p * 64 + lane];
    const float n1 = feat1[(size_t)ng * 64 + lane];

    float ap = u0 * p0 + u1 * p1;
    float an = u0 * n0 + u1 * n1;
    if (lane < 32) {
        const float u2 = feat2[(size_t)u * 32 + lane];
        const float p2 = feat2[(size_t)p * 32 + lane];
        const float n2 = feat2[(size_t)ng * 32 + lane];
        ap += u2 * p2;
        an += u2 * n2;
    }
#pragma unroll
    for (int off = 32; off > 0; off >>= 1) {
        ap += __shfl_xor(ap, off);
        an += __shfl_xor(an, off);
    }
    if (lane == 0) {
        out[i]         = ap;
        out[BATCH + i] = an;
    }
}

// ===========================================================================
extern "C" void kernel_launch(void* const* d_in, const int* in_sizes, int n_in,
                              void* d_out, int out_size, void* d_ws, size_t ws_size,
                              hipStream_t stream) {
    const int*   target       = (const int*)d_in[0];
    const int*   neighbor     = (const int*)d_in[1];
    const float* values       = (const float*)d_in[2];
    const int*   user_ids     = (const int*)d_in[3];
    const int*   pos_item_ids = (const int*)d_in[4];
    const int*   neg_item_ids = (const int*)d_in[5];
    const float* user_embed   = (const float*)d_in[6];
    const float* entity_embed = (const float*)d_in[7];
    const float* W1_0 = (const float*)d_in[8];
    const float* b1_0 = (const float*)d_in[9];
    const float* W2_0 = (const float*)d_in[10];
    const float* b2_0 = (const float*)d_in[11];
    const float* W1_1 = (const float*)d_in[12];
    const float* b1_1 = (const float*)d_in[13];
    const float* W2_1 = (const float*)d_in[14];
    const float* b2_1 = (const float*)d_in[15];

    // Workspace layout (bytes):
    //   (unused)@ 0           : 38,400,000   (former feat0 slot)
    //   feat1   @ 38,400,000  : 38,400,000
    //   feat2   @ 76,800,000  : 19,200,000   (hosts packed col during
    //                                         CSR+pull; feat2 written last)
    //   hneigh  @ 96,000,000  : 38,400,000
    //   row_ptr @ 134,400,000 :    600,064   (150001 ints)
    //   cursor  @ 135,000,064 :    600,000   (doubles as histogram counts)
    //   blk_sums@ 135,600,064 :      1,024
    char* ws = (char*)d_ws;
    float* feat1   = (float*)(ws + 38400000);
    float* feat2   = (float*)(ws + 76800000);
    int2*  col     = (int2*) (ws + 76800000);   // 2.4M x 8B = 19.2 MB
    float* hneigh  = (float*)(ws + 96000000);
    int*   row_ptr = (int*)  (ws + 134400000);
    int*   cursor  = (int*)  (ws + 135000064);
    int*   blk_sums= (int*)  (ws + 135600064);

    // ---- CSR build (once; edges identical for both layers) ----
    hipMemsetAsync(cursor, 0, (size_t)N_NODES * sizeof(int), stream);
    hist_kernel <<<2048, 256, 0, stream>>>(target, cursor, N_EDGES);
    scan1_kernel<<<SCAN_NBLK, 256, 0, stream>>>(cursor, row_ptr, blk_sums, N_NODES);
    scan2_kernel<<<1, 256, 0, stream>>>(blk_sums, SCAN_NBLK);
    scan3_kernel<<<(N_NODES + 255) / 256, 256, 0, stream>>>(row_ptr, cursor,
                                                            blk_sums, N_NODES);
    fill_kernel <<<2048, 256, 0, stream>>>(target, neighbor, values, cursor,
                                           col, N_EDGES);

    // ---- Layer 0 (64 -> 64), reading the split embedding tables ----
    pull_kernel<true><<<2048, 256, 0, stream>>>(nullptr, user_embed, entity_embed,
                                                row_ptr, col, hneigh, N_NODES);
    dense_layer_kernel<64, true><<<2048, 256, 0, stream>>>(
        nullptr, user_embed, entity_embed, hneigh,
        W1_0, b1_0, W2_0, b2_0, feat1, N_NODES);

    // ---- Layer 1 (64 -> 32) ----
    pull_kernel<false><<<2048, 256, 0, stream>>>(feat1, nullptr, nullptr,
                                                 row_ptr, col, hneigh, N_NODES);
    dense_layer_kernel<32, false><<<2048, 256, 0, stream>>>(
        feat1, nullptr, nullptr, hneigh,
        W1_1, b1_1, W2_1, b2_1, feat2, N_NODES);

    // ---- Scoring ----
    score_kernel<<<(BATCH * 64) / 256, 256, 0, stream>>>(user_embed, entity_embed,
                                                         feat1, feat2,
                                                         user_ids, pos_item_ids,
                                                         neg_item_ids,
                                                         (float*)d_out);
}

// Round 10
// 758.278 us; speedup vs baseline: 5.8970x; 1.0071x over previous
//
#include <hip/hip_runtime.h>
#include <math.h>

#define N_USERS    50000
#define N_ENTITIES 100000
#define N_NODES    150000
#define EMBED_DIM  64
#define N_EDGES    2400000
#define BATCH      4096
#define NEG_SLOPE  0.01f
#define L2_EPS     1e-12f

#define SCAN_CHUNK 1024
#define SCAN_NBLK  147   // ceil(150000/1024)
#define FILL_GROUPS 8          // one per XCD (blockIdx%8 heuristic)
#define TGT_PER_GRP 18750      // 150000 / 8

// Row source for layer-0 (no materialized concat): branch user/entity table.
template <bool SPLIT>
__device__ __forceinline__ const float* node_row(const float* __restrict__ feat,
                                                 const float* __restrict__ ue,
                                                 const float* __restrict__ ee,
                                                 int node) {
    if (SPLIT)
        return (node < N_USERS) ? ue + (size_t)node * 64
                                : ee + (size_t)(node - N_USERS) * 64;
    return feat + (size_t)node * 64;
}

// ===========================================================================
// CSR build: histogram -> prefix scan -> permutation fill (packed int2).
// ===========================================================================
__global__ __launch_bounds__(256)
void hist_kernel(const int* __restrict__ target, int* __restrict__ cnt, int n) {
    int i = blockIdx.x * blockDim.x + threadIdx.x;
    const int stride = gridDim.x * blockDim.x;
    for (; i < n; i += stride) atomicAdd(&cnt[target[i]], 1);
}

__global__ __launch_bounds__(256)
void scan1_kernel(const int* __restrict__ cnt, int* __restrict__ prescan,
                  int* __restrict__ blk_sums, int n) {
    __shared__ int s[256];
    const int b = blockIdx.x, t = threadIdx.x;
    const int idx = b * SCAN_CHUNK + t * 4;
    const int v0 = (idx + 0 < n) ? cnt[idx + 0] : 0;
    const int v1 = (idx + 1 < n) ? cnt[idx + 1] : 0;
    const int v2 = (idx + 2 < n) ? cnt[idx + 2] : 0;
    const int v3 = (idx + 3 < n) ? cnt[idx + 3] : 0;
    s[t] = v0 + v1 + v2 + v3;
    __syncthreads();
#pragma unroll
    for (int off = 1; off < 256; off <<= 1) {
        const int x = (t >= off) ? s[t - off] : 0;
        __syncthreads();
        s[t] += x;
        __syncthreads();
    }
    const int excl = (t == 0) ? 0 : s[t - 1];
    if (idx + 0 < n) prescan[idx + 0] = excl;
    if (idx + 1 < n) prescan[idx + 1] = excl + v0;
    if (idx + 2 < n) prescan[idx + 2] = excl + v0 + v1;
    if (idx + 3 < n) prescan[idx + 3] = excl + v0 + v1 + v2;
    if (t == 255) blk_sums[b] = s[255];
}

__global__ __launch_bounds__(256)
void scan2_kernel(int* __restrict__ blk_sums, int nblk) {
    __shared__ int s[256];
    const int t = threadIdx.x;
    s[t] = (t < nblk) ? blk_sums[t] : 0;
    __syncthreads();
#pragma unroll
    for (int off = 1; off < 256; off <<= 1) {
        const int x = (t >= off) ? s[t - off] : 0;
        __syncthreads();
        s[t] += x;
        __syncthreads();
    }
    if (t < nblk) blk_sums[t] = (t == 0) ? 0 : s[t - 1];
}

__global__ __launch_bounds__(256)
void scan3_kernel(int* __restrict__ row_ptr, int* __restrict__ cursor,
                  const int* __restrict__ blk_off, int n) {
    const int i = blockIdx.x * blockDim.x + threadIdx.x;
    if (i < n) {
        const int v = row_ptr[i] + blk_off[i >> 10];
        row_ptr[i] = v;
        cursor[i]  = v;
    }
    if (i == 0) row_ptr[n] = N_EDGES;
}

// XCD-grouped fill: group g (= blockIdx%8, the round-robin XCD heuristic)
// scans the ENTIRE edge list but only processes edges whose target falls in
// its 18750-target range. All writes to any 64B line of col then come from
// one block-group -> one XCD's L2 -> the line is written back ONCE instead
// of 8 partial-sector writebacks (round-9 counters: 150 MB writes for
// 19.2 MB payload). The 8x redundant target reads are L3-resident.
__global__ __launch_bounds__(256)
void fill_kernel(const int* __restrict__ target, const int* __restrict__ neighbor,
                 const float* __restrict__ values, int* __restrict__ cursor,
                 int2* __restrict__ col, int n) {
    const int group  = blockIdx.x & (FILL_GROUPS - 1);
    int i            = (blockIdx.x >> 3) * blockDim.x + threadIdx.x;
    const int stride = (gridDim.x >> 3) * blockDim.x;
    for (; i < n; i += stride) {
        const int t = target[i];
        if (t / TGT_PER_GRP == group) {
            const int p = atomicAdd(&cursor[t], 1);
            col[p] = make_int2(neighbor[i], __float_as_int(values[i]));
        }
    }
}

// ===========================================================================
// Pull aggregation: h_neigh[r] = sum over in-edges of feat[nbr]*v.
// One wave per row, lane = dim; packed int2 edge reads (wave-uniform
// broadcast); 8-deep gather unroll (was 4) for more memory-level
// parallelism; one coalesced 256B store; no f32 atomics.
// ===========================================================================
template <bool SPLIT>
__global__ __launch_bounds__(256)
void pull_kernel(const float* __restrict__ feat,
                 const float* __restrict__ ue,
                 const float* __restrict__ ee,
                 const int*   __restrict__ row_ptr,
                 const int2*  __restrict__ col,
                 float*       __restrict__ hneigh,
                 int nrows) {
    const int lane   = threadIdx.x & 63;
    const int gwave  = (blockIdx.x * blockDim.x + threadIdx.x) >> 6;
    const int nwaves = (gridDim.x * blockDim.x) >> 6;

    for (int r = gwave; r < nrows; r += nwaves) {
        const int s = row_ptr[r];
        const int e = row_ptr[r + 1];
        float a0 = 0.f, a1 = 0.f, a2 = 0.f, a3 = 0.f;
        float a4 = 0.f, a5 = 0.f, a6 = 0.f, a7 = 0.f;
        int i = s;
        for (; i + 7 < e; i += 8) {
            const int2 c0 = col[i + 0], c1 = col[i + 1];
            const int2 c2 = col[i + 2], c3 = col[i + 3];
            const int2 c4 = col[i + 4], c5 = col[i + 5];
            const int2 c6 = col[i + 6], c7 = col[i + 7];
            a0 += node_row<SPLIT>(feat, ue, ee, c0.x)[lane] * __int_as_float(c0.y);
            a1 += node_row<SPLIT>(feat, ue, ee, c1.x)[lane] * __int_as_float(c1.y);
            a2 += node_row<SPLIT>(feat, ue, ee, c2.x)[lane] * __int_as_float(c2.y);
            a3 += node_row<SPLIT>(feat, ue, ee, c3.x)[lane] * __int_as_float(c3.y);
            a4 += node_row<SPLIT>(feat, ue, ee, c4.x)[lane] * __int_as_float(c4.y);
            a5 += node_row<SPLIT>(feat, ue, ee, c5.x)[lane] * __int_as_float(c5.y);
            a6 += node_row<SPLIT>(feat, ue, ee, c6.x)[lane] * __int_as_float(c6.y);
            a7 += node_row<SPLIT>(feat, ue, ee, c7.x)[lane] * __int_as_float(c7.y);
        }
        if (i + 3 < e) {
            const int2 c0 = col[i + 0], c1 = col[i + 1];
            const int2 c2 = col[i + 2], c3 = col[i + 3];
            a0 += node_row<SPLIT>(feat, ue, ee, c0.x)[lane] * __int_as_float(c0.y);
            a1 += node_row<SPLIT>(feat, ue, ee, c1.x)[lane] * __int_as_float(c1.y);
            a2 += node_row<SPLIT>(feat, ue, ee, c2.x)[lane] * __int_as_float(c2.y);
            a3 += node_row<SPLIT>(feat, ue, ee, c3.x)[lane] * __int_as_float(c3.y);
            i += 4;
        }
        for (; i < e; ++i) {
            const int2 c = col[i];
            a0 += node_row<SPLIT>(feat, ue, ee, c.x)[lane] * __int_as_float(c.y);
        }
        hneigh[(size_t)r * 64 + lane] =
            ((a0 + a1) + (a2 + a3)) + ((a4 + a5) + (a6 + a7));
    }
}

// ===========================================================================
// Dense bi-interaction layer + LeakyReLU + L2 normalize.  (unchanged from
// round 9 — verified: left the top-5 after the (256,1) + padded-LDS fix)
// ===========================================================================
template <int OUT, bool SPLIT>
__global__ __launch_bounds__(256, 1)
void dense_layer_kernel(const float* __restrict__ feat,
                        const float* __restrict__ ue,
                        const float* __restrict__ ee,
                        const float* __restrict__ hneigh,
                        const float* __restrict__ W1,
                        const float* __restrict__ b1,
                        const float* __restrict__ W2,
                        const float* __restrict__ b2,
                        float* __restrict__ out,
                        int nrows) {
    constexpr int IN  = 64;
    constexpr int LDP = OUT + 1;          // padded stride: banks spread
    __shared__ float w1t[IN * LDP];       // [k][j] transposed, padded
    __shared__ float w2t[IN * LDP];

    const int tid = threadIdx.x;
    for (int idx = tid; idx < IN * OUT; idx += blockDim.x) {
        const int j = idx / IN;
        const int k = idx % IN;
        w1t[k * LDP + j] = W1[idx];
        w2t[k * LDP + j] = W2[idx];
    }
    __syncthreads();

    const int lane = tid & 63;
    const int j    = lane & (OUT - 1);

    // Per-lane register copy of weight column j (128 VGPRs).
    float w1[IN], w2[IN];
#pragma unroll
    for (int k = 0; k < IN; ++k) {
        w1[k] = w1t[k * LDP + j];
        w2[k] = w2t[k * LDP + j];
    }
    const float bias = b1[j] + b2[j];

    const int gwave  = (blockIdx.x * blockDim.x + tid) >> 6;
    const int nwaves = (gridDim.x * blockDim.x) >> 6;

    int row = gwave;
    if (row < nrows) {
        float f  = node_row<SPLIT>(feat, ue, ee, row)[lane];
        float hn = hneigh[(size_t)row * IN + lane];
        while (true) {
            const int nrow = row + nwaves;
            float fN, hnN;
            if (nrow < nrows) {               // prefetch next row
                fN  = node_row<SPLIT>(feat, ue, ee, nrow)[lane];
                hnN = hneigh[(size_t)nrow * IN + lane];
            }

            const float sv = f + hn;
            const float pv = f * hn;

            float acc = bias;
#pragma unroll
            for (int k = 0; k < IN; ++k) {
                const float sk = __uint_as_float(
                    __builtin_amdgcn_readlane(__float_as_uint(sv), k));
                const float pk = __uint_as_float(
                    __builtin_amdgcn_readlane(__float_as_uint(pv), k));
                acc += sk * w1[k] + pk * w2[k];
            }

            float hval = (acc >= 0.0f) ? acc : NEG_SLOPE * acc;

            float sq = (lane < OUT) ? hval * hval : 0.0f;
            float ss = sq;
#pragma unroll
            for (int off = 32; off > 0; off >>= 1) ss += __shfl_xor(ss, off);
            const float nrm   = sqrtf(ss);
            const float scale = 1.0f / fmaxf(nrm, L2_EPS);

            if (lane < OUT) out[(size_t)row * OUT + lane] = hval * scale;

            if (nrow >= nrows) break;
            row = nrow; f = fN; hn = hnN;
        }
    }
}

// ===========================================================================
// Final scoring. One wave per sample.
// ===========================================================================
__global__ __launch_bounds__(256)
void score_kernel(const float* __restrict__ ue,     // (N_USERS,64)
                  const float* __restrict__ ee,     // (N_ENTITIES,64)
                  const float* __restrict__ feat1,  // (N,64)
                  const float* __restrict__ feat2,  // (N,32)
                  const int* __restrict__ user_ids,
                  const int* __restrict__ pos_ids,
                  const int* __restrict__ neg_ids,
                  float* __restrict__ out) {
    const int lane = threadIdx.x & 63;
    const int i    = (blockIdx.x * blockDim.x + threadIdx.x) >> 6;
    if (i >= BATCH) return;

    const int uid = user_ids[i];
    const int pid = pos_ids[i];
    const int nid = neg_ids[i];
    const int u  = uid;
    const int p  = N_USERS + pid;
    const int ng = N_USERS + nid;

    const float u0 = ue[(size_t)uid * 64 + lane];
    const float p0 = ee[(size_t)pid * 64 + lane];
    const float n0 = ee[(size_t)nid * 64 + lane];
    const float u1 = feat1[(size_t)u * 64 + lane];
    const float p1 = feat1[(size_t)p * 64 + lane];
    const float n1 = feat1[(size_t)ng * 64 + lane];

    float ap = u0 * p0 + u1 * p1;
    float an = u0 * n0 + u1 * n1;
    if (lane < 32) {
        const float u2 = feat2[(size_t)u * 32 + lane];
        const float p2 = feat2[(size_t)p * 32 + lane];
        const float n2 = feat2[(size_t)ng * 32 + lane];
        ap += u2 * p2;
        an += u2 * n2;
    }
#pragma unroll
    for (int off = 32; off > 0; off >>= 1) {
        ap += __shfl_xor(ap, off);
        an += __shfl_xor(an, off);
    }
    if (lane == 0) {
        out[i]         = ap;
        out[BATCH + i] = an;
    }
}

// ===========================================================================
extern "C" void kernel_launch(void* const* d_in, const int* in_sizes, int n_in,
                              void* d_out, int out_size, void* d_ws, size_t ws_size,
                              hipStream_t stream) {
    const int*   target       = (const int*)d_in[0];
    const int*   neighbor     = (const int*)d_in[1];
    const float* values       = (const float*)d_in[2];
    const int*   user_ids     = (const int*)d_in[3];
    const int*   pos_item_ids = (const int*)d_in[4];
    const int*   neg_item_ids = (const int*)d_in[5];
    const float* user_embed   = (const float*)d_in[6];
    const float* entity_embed = (const float*)d_in[7];
    const float* W1_0 = (const float*)d_in[8];
    const float* b1_0 = (const float*)d_in[9];
    const float* W2_0 = (const float*)d_in[10];
    const float* b2_0 = (const float*)d_in[11];
    const float* W1_1 = (const float*)d_in[12];
    const float* b1_1 = (const float*)d_in[13];
    const float* W2_1 = (const float*)d_in[14];
    const float* b2_1 = (const float*)d_in[15];

    // Workspace layout (bytes):
    //   (unused)@ 0           : 38,400,000   (former feat0 slot)
    //   feat1   @ 38,400,000  : 38,400,000
    //   feat2   @ 76,800,000  : 19,200,000   (hosts packed col during
    //                                         CSR+pull; feat2 written last)
    //   hneigh  @ 96,000,000  : 38,400,000
    //   row_ptr @ 134,400,000 :    600,064   (150001 ints)
    //   cursor  @ 135,000,064 :    600,000   (doubles as histogram counts)
    //   blk_sums@ 135,600,064 :      1,024
    char* ws = (char*)d_ws;
    float* feat1   = (float*)(ws + 38400000);
    float* feat2   = (float*)(ws + 76800000);
    int2*  col     = (int2*) (ws + 76800000);   // 2.4M x 8B = 19.2 MB
    float* hneigh  = (float*)(ws + 96000000);
    int*   row_ptr = (int*)  (ws + 134400000);
    int*   cursor  = (int*)  (ws + 135000064);
    int*   blk_sums= (int*)  (ws + 135600064);

    // ---- CSR build (once; edges identical for both layers) ----
    hipMemsetAsync(cursor, 0, (size_t)N_NODES * sizeof(int), stream);
    hist_kernel <<<2048, 256, 0, stream>>>(target, cursor, N_EDGES);
    scan1_kernel<<<SCAN_NBLK, 256, 0, stream>>>(cursor, row_ptr, blk_sums, N_NODES);
    scan2_kernel<<<1, 256, 0, stream>>>(blk_sums, SCAN_NBLK);
    scan3_kernel<<<(N_NODES + 255) / 256, 256, 0, stream>>>(row_ptr, cursor,
                                                            blk_sums, N_NODES);
    fill_kernel <<<2048, 256, 0, stream>>>(target, neighbor, values, cursor,
                                           col, N_EDGES);

    // ---- Layer 0 (64 -> 64), reading the split embedding tables ----
    pull_kernel<true><<<2048, 256, 0, stream>>>(nullptr, user_embed, entity_embed,
                                                row_ptr, col, hneigh, N_NODES);
    dense_layer_kernel<64, true><<<2048, 256, 0, stream>>>(
        nullptr, user_embed, entity_embed, hneigh,
        W1_0, b1_0, W2_0, b2_0, feat1, N_NODES);

    // ---- Layer 1 (64 -> 32) ----
    pull_kernel<false><<<2048, 256, 0, stream>>>(feat1, nullptr, nullptr,
                                                 row_ptr, col, hneigh, N_NODES);
    dense_layer_kernel<32, false><<<2048, 256, 0, stream>>>(
        feat1, nullptr, nullptr, hneigh,
        W1_1, b1_1, W2_1, b2_1, feat2, N_NODES);

    // ---- Scoring ----
    score_kernel<<<(BATCH * 64) / 256, 256, 0, stream>>>(user_embed, entity_embed,
                                                         feat1, feat2,
                                                         user_ids, pos_item_ids,
                                                         neg_item_ids,
                                                         (float*)d_out);
}